// Round 1
// baseline (264.837 us; speedup 1.0000x reference)
//
#include <hip/hip_runtime.h>
#include <hip/hip_bf16.h>

typedef unsigned short u16;
typedef __attribute__((ext_vector_type(8))) short bf16x8;  // 8 bf16 (4 VGPRs)
typedef __attribute__((ext_vector_type(4))) float f32x4;

#define DEVI __device__ __forceinline__

DEVI u16 f2bf(float f) {
  union { float f; unsigned int u; } v; v.f = f;
  unsigned int u = v.u;
  unsigned int r = (u + 0x7fffu + ((u >> 16) & 1u)) >> 16;  // RNE
  return (u16)r;
}

// ---------------- fp32 -> bf16 conversion ----------------
__global__ __launch_bounds__(256) void cvt_kernel(const float4* __restrict__ in,
                                                  u16* __restrict__ out, int n4) {
  int i = blockIdx.x * 256 + threadIdx.x;
  if (i < n4) {
    float4 f = in[i];
    ushort4 o;
    o.x = f2bf(f.x); o.y = f2bf(f.y); o.z = f2bf(f.z); o.w = f2bf(f.w);
    ((ushort4*)out)[i] = o;
  }
}

// ---------------- in_proj GEMM: qvk = x @ w_in^T + b_in ----------------
// M=4096 (B*S), K=512, N=1536. Output routed: cols 0..511 -> Q, 512..1023 -> V
// (chunk-order quirk: q, v, k), 1024..1535 -> K. Q,K as [bh][S][64] bf16,
// V transposed as [bh][64][S] bf16 so PV B-fragments are contiguous.
__global__ __launch_bounds__(256) void inproj_gemm(
    const u16* __restrict__ xb, const u16* __restrict__ wb,
    const float* __restrict__ bin,
    u16* __restrict__ Qb, u16* __restrict__ Kb, u16* __restrict__ Vt) {
  const int K = 512;
  int wave = threadIdx.x >> 6;
  int lane = threadIdx.x & 63;
  int ql = lane & 15, quad = lane >> 4;
  int mbase = blockIdx.x * 64 + wave * 16;
  int nbase = blockIdx.y * 64;

  f32x4 acc[4] = {{0,0,0,0},{0,0,0,0},{0,0,0,0},{0,0,0,0}};
  const u16* ap  = xb + (mbase + ql) * K + quad * 8;
  const u16* bp0 = wb + (nbase +      ql) * K + quad * 8;
  const u16* bp1 = wb + (nbase + 16 + ql) * K + quad * 8;
  const u16* bp2 = wb + (nbase + 32 + ql) * K + quad * 8;
  const u16* bp3 = wb + (nbase + 48 + ql) * K + quad * 8;
#pragma unroll 4
  for (int k0 = 0; k0 < K; k0 += 32) {
    bf16x8 a  = *(const bf16x8*)(ap + k0);
    bf16x8 b0 = *(const bf16x8*)(bp0 + k0);
    bf16x8 b1 = *(const bf16x8*)(bp1 + k0);
    bf16x8 b2 = *(const bf16x8*)(bp2 + k0);
    bf16x8 b3 = *(const bf16x8*)(bp3 + k0);
    acc[0] = __builtin_amdgcn_mfma_f32_16x16x32_bf16(a, b0, acc[0], 0, 0, 0);
    acc[1] = __builtin_amdgcn_mfma_f32_16x16x32_bf16(a, b1, acc[1], 0, 0, 0);
    acc[2] = __builtin_amdgcn_mfma_f32_16x16x32_bf16(a, b2, acc[2], 0, 0, 0);
    acc[3] = __builtin_amdgcn_mfma_f32_16x16x32_bf16(a, b3, acc[3], 0, 0, 0);
  }
#pragma unroll
  for (int t = 0; t < 4; ++t) {
    int n = nbase + t * 16 + ql;
    float bias = bin[n];
    int chunk = n >> 9;       // 0=q, 1=v, 2=k
    int nc = n & 511;
    int h = nc >> 6, d = nc & 63;
#pragma unroll
    for (int r = 0; r < 4; ++r) {
      int m = mbase + quad * 4 + r;    // C/D row = quad*4+reg
      int b = m >> 11, s = m & 2047;
      u16 val = f2bf(acc[t][r] + bias);
      int bh = b * 8 + h;
      if (chunk == 0)      Qb[(bh * 2048 + s) * 64 + d] = val;
      else if (chunk == 2) Kb[(bh * 2048 + s) * 64 + d] = val;
      else                 Vt[(bh * 64 + d) * 2048 + s] = val;
    }
  }
}

// ---------------- flash attention (causal) ----------------
// grid (32 qblocks, 16 bh), 256 threads = 4 waves; wave owns 16 q-rows.
__global__ __launch_bounds__(256) void attn_kernel(
    const u16* __restrict__ Qb, const u16* __restrict__ Kb,
    const u16* __restrict__ Vt, u16* __restrict__ Ob) {
  const int S = 2048;
  int wave = threadIdx.x >> 6, lane = threadIdx.x & 63;
  int ql = lane & 15, quad = lane >> 4;
  int qblk = blockIdx.x, bh = blockIdx.y;
  int qbase = qblk * 64 + wave * 16;
  const u16* Qh = Qb + bh * S * 64;
  const u16* Kh = Kb + bh * S * 64;
  const u16* Vh = Vt + bh * 64 * S;

  // per-wave P staging: 16 rows x 32 keys, row stride 40 shorts (16B-aligned rows)
  __shared__ u16 pbuf[4][16 * 40];
  u16* pw = pbuf[wave];

  bf16x8 q0 = *(const bf16x8*)(Qh + (qbase + ql) * 64 + quad * 8);
  bf16x8 q1 = *(const bf16x8*)(Qh + (qbase + ql) * 64 + 32 + quad * 8);
  f32x4 o0 = {0,0,0,0}, o1 = {0,0,0,0}, o2 = {0,0,0,0}, o3 = {0,0,0,0};
  float m_r[4], l_r[4];
#pragma unroll
  for (int r = 0; r < 4; ++r) { m_r[r] = -3.0e38f; l_r[r] = 0.0f; }

  int nkb = (qbase >> 5) + 1;  // causal: key blocks of 32 with kbase <= qbase
  for (int kb = 0; kb < nkb; ++kb) {
    int kbase = kb * 32;
    const u16* kp0 = Kh + (kbase + ql) * 64 + quad * 8;
    const u16* kp1 = Kh + (kbase + 16 + ql) * 64 + quad * 8;
    f32x4 s0 = {0,0,0,0}, s1 = {0,0,0,0};
    s0 = __builtin_amdgcn_mfma_f32_16x16x32_bf16(q0, *(const bf16x8*)(kp0), s0, 0, 0, 0);
    s0 = __builtin_amdgcn_mfma_f32_16x16x32_bf16(q1, *(const bf16x8*)(kp0 + 32), s0, 0, 0, 0);
    s1 = __builtin_amdgcn_mfma_f32_16x16x32_bf16(q0, *(const bf16x8*)(kp1), s1, 0, 0, 0);
    s1 = __builtin_amdgcn_mfma_f32_16x16x32_bf16(q1, *(const bf16x8*)(kp1 + 32), s1, 0, 0, 0);

    bool maskblk = (kbase + 31 > qbase);
    float sc0[4], sc1[4];
#pragma unroll
    for (int r = 0; r < 4; ++r) {
      int qrow = qbase + quad * 4 + r;
      float a0 = s0[r] * 0.125f;  // 1/sqrt(64)
      float a1 = s1[r] * 0.125f;
      if (maskblk) {
        if (kbase + ql > qrow)      a0 = -3.0e38f;
        if (kbase + 16 + ql > qrow) a1 = -3.0e38f;
      }
      sc0[r] = a0; sc1[r] = a1;
    }
    // row-max over the 16 lanes holding this row's 32 keys
    float mx[4];
#pragma unroll
    for (int r = 0; r < 4; ++r) mx[r] = fmaxf(sc0[r], sc1[r]);
#pragma unroll
    for (int off = 1; off < 16; off <<= 1) {
#pragma unroll
      for (int r = 0; r < 4; ++r) mx[r] = fmaxf(mx[r], __shfl_xor(mx[r], off));
    }
    float alpha[4], p0[4], p1[4], rsum[4];
#pragma unroll
    for (int r = 0; r < 4; ++r) {
      float mn = fmaxf(m_r[r], mx[r]);
      alpha[r] = __expf(m_r[r] - mn);   // 0 on first block
      m_r[r] = mn;
      p0[r] = __expf(sc0[r] - mn);
      p1[r] = __expf(sc1[r] - mn);
      rsum[r] = p0[r] + p1[r];
    }
#pragma unroll
    for (int off = 1; off < 16; off <<= 1) {
#pragma unroll
      for (int r = 0; r < 4; ++r) rsum[r] += __shfl_xor(rsum[r], off);
    }
#pragma unroll
    for (int r = 0; r < 4; ++r) {
      l_r[r] = l_r[r] * alpha[r] + rsum[r];
      int prow = quad * 4 + r;
      pw[prow * 40 + ql]      = f2bf(p0[r]);
      pw[prow * 40 + 16 + ql] = f2bf(p1[r]);
      o0[r] *= alpha[r]; o1[r] *= alpha[r]; o2[r] *= alpha[r]; o3[r] *= alpha[r];
    }
    // same-wave DS write->read: drain LDS queue (waves have unequal trip
    // counts, so no __syncthreads may appear in this loop)
    asm volatile("s_waitcnt lgkmcnt(0)" ::: "memory");
    bf16x8 pf = *(const bf16x8*)(pw + ql * 40 + quad * 8);  // A-layout fragment
    const u16* vp = Vh + ql * S + kbase + quad * 8;
    o0 = __builtin_amdgcn_mfma_f32_16x16x32_bf16(pf, *(const bf16x8*)(vp),          o0, 0, 0, 0);
    o1 = __builtin_amdgcn_mfma_f32_16x16x32_bf16(pf, *(const bf16x8*)(vp + 16 * S), o1, 0, 0, 0);
    o2 = __builtin_amdgcn_mfma_f32_16x16x32_bf16(pf, *(const bf16x8*)(vp + 32 * S), o2, 0, 0, 0);
    o3 = __builtin_amdgcn_mfma_f32_16x16x32_bf16(pf, *(const bf16x8*)(vp + 48 * S), o3, 0, 0, 0);
  }
  // epilogue: O/l -> Ob [4096][512] bf16, head-interleaved columns
  int b = bh >> 3, h = bh & 7;
#pragma unroll
  for (int r = 0; r < 4; ++r) {
    float inv = 1.0f / l_r[r];
    int row = (b * 2048 + qbase + quad * 4 + r) * 512 + h * 64;
    Ob[row + ql]      = f2bf(o0[r] * inv);
    Ob[row + 16 + ql] = f2bf(o1[r] * inv);
    Ob[row + 32 + ql] = f2bf(o2[r] * inv);
    Ob[row + 48 + ql] = f2bf(o3[r] * inv);
  }
}

// ---------------- out_proj GEMM: out = O @ w_out^T + b_out (fp32 out) ----------------
__global__ __launch_bounds__(256) void outproj_gemm(
    const u16* __restrict__ Ob, const u16* __restrict__ wb,
    const float* __restrict__ bout, float* __restrict__ out) {
  const int K = 512;
  int wave = threadIdx.x >> 6;
  int lane = threadIdx.x & 63;
  int ql = lane & 15, quad = lane >> 4;
  int mbase = blockIdx.x * 64 + wave * 16;
  int nbase = blockIdx.y * 64;

  f32x4 acc[4] = {{0,0,0,0},{0,0,0,0},{0,0,0,0},{0,0,0,0}};
  const u16* ap  = Ob + (mbase + ql) * K + quad * 8;
  const u16* bp0 = wb + (nbase +      ql) * K + quad * 8;
  const u16* bp1 = wb + (nbase + 16 + ql) * K + quad * 8;
  const u16* bp2 = wb + (nbase + 32 + ql) * K + quad * 8;
  const u16* bp3 = wb + (nbase + 48 + ql) * K + quad * 8;
#pragma unroll 4
  for (int k0 = 0; k0 < K; k0 += 32) {
    bf16x8 a  = *(const bf16x8*)(ap + k0);
    bf16x8 b0 = *(const bf16x8*)(bp0 + k0);
    bf16x8 b1 = *(const bf16x8*)(bp1 + k0);
    bf16x8 b2 = *(const bf16x8*)(bp2 + k0);
    bf16x8 b3 = *(const bf16x8*)(bp3 + k0);
    acc[0] = __builtin_amdgcn_mfma_f32_16x16x32_bf16(a, b0, acc[0], 0, 0, 0);
    acc[1] = __builtin_amdgcn_mfma_f32_16x16x32_bf16(a, b1, acc[1], 0, 0, 0);
    acc[2] = __builtin_amdgcn_mfma_f32_16x16x32_bf16(a, b2, acc[2], 0, 0, 0);
    acc[3] = __builtin_amdgcn_mfma_f32_16x16x32_bf16(a, b3, acc[3], 0, 0, 0);
  }
#pragma unroll
  for (int t = 0; t < 4; ++t) {
    int n = nbase + t * 16 + ql;
    float bias = bout[n];
#pragma unroll
    for (int r = 0; r < 4; ++r) {
      int m = mbase + quad * 4 + r;
      out[m * 512 + n] = acc[t][r] + bias;
    }
  }
}

extern "C" void kernel_launch(void* const* d_in, const int* in_sizes, int n_in,
                              void* d_out, int out_size, void* d_ws, size_t ws_size,
                              hipStream_t stream) {
  const float* x     = (const float*)d_in[0];  // [2,2048,512]
  const float* w_in  = (const float*)d_in[1];  // [1536,512]
  const float* b_in  = (const float*)d_in[2];  // [1536]
  const float* w_out = (const float*)d_in[3];  // [512,512]
  const float* b_out = (const float*)d_in[4];  // [512]
  float* out = (float*)d_out;                  // [2,2048,512] fp32
  char* ws = (char*)d_ws;

  // ws layout (bytes), all 16B-aligned
  u16* xb    = (u16*)(ws);             // 4096x512 bf16   (4 MB)
  u16* winb  = (u16*)(ws + 4194304);   // 1536x512 bf16   (1.5 MB)
  u16* woutb = (u16*)(ws + 5767168);   // 512x512 bf16    (0.5 MB)
  u16* Qb    = (u16*)(ws + 6291456);   // [16][2048][64]  (4 MB)
  u16* Kb    = (u16*)(ws + 10485760);  // [16][2048][64]  (4 MB)
  u16* Vt    = (u16*)(ws + 14680064);  // [16][64][2048]  (4 MB)
  u16* Ob    = (u16*)(ws + 18874368);  // [4096][512]     (4 MB)

  cvt_kernel<<<2048, 256, 0, stream>>>((const float4*)x, xb, 524288);
  cvt_kernel<<<768, 256, 0, stream>>>((const float4*)w_in, winb, 196608);
  cvt_kernel<<<256, 256, 0, stream>>>((const float4*)w_out, woutb, 65536);
  inproj_gemm<<<dim3(64, 24), 256, 0, stream>>>(xb, winb, b_in, Qb, Kb, Vt);
  attn_kernel<<<dim3(32, 16), 256, 0, stream>>>(Qb, Kb, Vt, Ob);
  outproj_gemm<<<dim3(64, 8), 256, 0, stream>>>(Ob, woutb, b_out, out);
}